// Round 16
// baseline (134.102 us; speedup 1.0000x reference)
//
#include <hip/hip_runtime.h>

#define TPB 256
#define TPBG 512           // gather kernels: 64 nodes x 8 lanes
#define ACHUNK 4096        // edges per fill block (256 thr x 16, register-staged)
#define BSHIFT 6           // bucket = dst >> 6  (64 nodes/bucket)
#define BNODES 64
#define CAP 2048           // tmp capacity per bucket (mean 1024; padded CSR <= ~1.6K)
#define GROWS 128          // gemm1 tile rows
// gemm1 LDS: Xs bf16[128][136] = 34816 B, Wt bf16[64][136] = 17408 B
#define SMEMB 52224

typedef __attribute__((ext_vector_type(8))) short bf16x8;
typedef __attribute__((ext_vector_type(4))) float f32x4;

// ---- bf16 helpers (values finite; RNE encode) ----
__device__ __forceinline__ float blo(unsigned u) { return __uint_as_float(u << 16); }
__device__ __forceinline__ float bhi(unsigned u) { return __uint_as_float(u & 0xffff0000u); }
__device__ __forceinline__ unsigned pack2(float a, float b) {
    unsigned ua = __float_as_uint(a); ua += 0x7fffu + ((ua >> 16) & 1u);
    unsigned ub = __float_as_uint(b); ub += 0x7fffu + ((ub >> 16) & 1u);
    return (ua >> 16) | (ub & 0xffff0000u);
}
__device__ __forceinline__ void dec8(uint4 v, float* f) {
    f[0] = blo(v.x); f[1] = bhi(v.x); f[2] = blo(v.y); f[3] = bhi(v.y);
    f[4] = blo(v.z); f[5] = bhi(v.z); f[6] = blo(v.w); f[7] = bhi(v.w);
}
__device__ __forceinline__ void dec4(uint2 v, float* f) {
    f[0] = blo(v.x); f[1] = bhi(v.x); f[2] = blo(v.y); f[3] = bhi(v.y);
}

// ---------------- fat: fill (packed tmp, R1-verified) || GEMM1 via bf16 MFMA (R10) ----------------
// tmp[e] = (dst&63)<<16 | src   (src < 65536 since N=50000)
// h1b holds UNSCALED X@W1 rows bf16; dinv applied at gather time in k_gg.
// MFMA branch: 128x64 tile/block, 4 waves x (32 rows x 64 cols), K=128 in 4 steps of 32.
// C/D layout (HW-verified): col = lane&15, row = (lane>>4)*4 + reg.

__global__ __launch_bounds__(TPB) void k_fat(
        const int* __restrict__ src, const int* __restrict__ dst, int E,
        int* __restrict__ bcnt, int* __restrict__ tmp, int NB,
        const float* __restrict__ X, const float* __restrict__ W,
        unsigned int* __restrict__ H1b, int N, int G1, int FB) {
    __shared__ __align__(16) char smem[SMEMB];
    int bid = blockIdx.x;
    int t = threadIdx.x;

    if ((bid % 3) == 0) {
        int* lcnt = (int*)smem;
        int fidx = bid / 3;
        if (fidx >= FB) return;
        int c0 = fidx * ACHUNK;
        int s_[16], d_[16];
#pragma unroll
        for (int i = 0; i < 16; i++) {
            int e = c0 + i * TPB + t;
            if (e < E) { s_[i] = src[e]; d_[i] = dst[e]; }
            else d_[i] = -1;
        }
        for (int b = t; b < NB; b += TPB) lcnt[b] = 0;
        __syncthreads();
#pragma unroll
        for (int i = 0; i < 16; i++)
            if (d_[i] >= 0) atomicAdd(&lcnt[d_[i] >> BSHIFT], 1);
        __syncthreads();
        for (int b = t; b < NB; b += TPB) {
            int c = lcnt[b];
            lcnt[b] = c ? (b * CAP + atomicAdd(&bcnt[b], c)) : 0;
        }
        __syncthreads();
#pragma unroll
        for (int i = 0; i < 16; i++) {
            if (d_[i] >= 0) {
                int bkt = d_[i] >> BSHIFT;
                int pos = atomicAdd(&lcnt[bkt], 1);
                if (pos < (bkt + 1) * CAP) {   // overflow guard (never hit)
                    tmp[pos] = ((d_[i] & (BNODES - 1)) << 16) | s_[i];
                }
            }
        }
    } else {
        int gb = bid - bid / 3 - 1;
        if (gb >= G1) return;
        int row0 = gb * GROWS;

        unsigned int* XsU32 = (unsigned int*)smem;             // [128][68] uints
        unsigned int* WtU32 = (unsigned int*)(smem + 34816);   // [64][68] uints
        const unsigned short* XsU = (const unsigned short*)smem;
        const unsigned short* WtU = (const unsigned short*)(smem + 34816);

        // stage X tile -> bf16 (row-major, padded stride 136 bf16)
        const float4* X4 = (const float4*)X;
#pragma unroll
        for (int i = 0; i < 16; i++) {
            int q = t + i * 256;          // 0..4095
            int r = q >> 5, c4 = q & 31;
            int gr = row0 + r; if (gr >= N) gr = N - 1;
            float4 v = X4[(size_t)gr * 32 + c4];
            unsigned int* dptr = XsU32 + r * 68 + c4 * 2;
            dptr[0] = pack2(v.x, v.y);
            dptr[1] = pack2(v.z, v.w);
        }
        // stage W1 TRANSPOSED -> bf16: Wt[col][k] (pairs along k)
#pragma unroll
        for (int i = 0; i < 16; i++) {
            int q = t + i * 256;          // 0..4095
            int col = q & 63, kp = q >> 6; // kp 0..63
            float w0 = W[(size_t)(2 * kp) * 64 + col];
            float w1 = W[(size_t)(2 * kp + 1) * 64 + col];
            WtU32[col * 68 + kp] = pack2(w0, w1);
        }
        __syncthreads();

        int lane = t & 63;
        int wv = t >> 6;                  // 4 waves: rows [wv*32, wv*32+32)
        int l15 = lane & 15;
        int lg = lane >> 4;
        f32x4 zero = {0.0f, 0.0f, 0.0f, 0.0f};
        f32x4 acc[2][4];
#pragma unroll
        for (int mt = 0; mt < 2; mt++)
#pragma unroll
            for (int nt = 0; nt < 4; nt++) acc[mt][nt] = zero;

#pragma unroll
        for (int kk = 0; kk < 4; kk++) {
            int ko = kk * 32 + lg * 8;    // bf16 index within row, 16B-aligned
            bf16x8 a0 = *reinterpret_cast<const bf16x8*>(XsU + (wv * 32 + l15) * 136 + ko);
            bf16x8 a1 = *reinterpret_cast<const bf16x8*>(XsU + (wv * 32 + 16 + l15) * 136 + ko);
            bf16x8 b[4];
#pragma unroll
            for (int nt = 0; nt < 4; nt++)
                b[nt] = *reinterpret_cast<const bf16x8*>(WtU + (nt * 16 + l15) * 136 + ko);
#pragma unroll
            for (int nt = 0; nt < 4; nt++) {
                acc[0][nt] = __builtin_amdgcn_mfma_f32_16x16x32_bf16(a0, b[nt], acc[0][nt], 0, 0, 0);
                acc[1][nt] = __builtin_amdgcn_mfma_f32_16x16x32_bf16(a1, b[nt], acc[1][nt], 0, 0, 0);
            }
        }
        __syncthreads();                   // done reading Xs; reuse as fp32 rows[128][68]

        float* rows = (float*)smem;
#pragma unroll
        for (int mt = 0; mt < 2; mt++)
#pragma unroll
            for (int nt = 0; nt < 4; nt++)
#pragma unroll
                for (int r = 0; r < 4; r++)
                    rows[(wv * 32 + mt * 16 + lg * 4 + r) * 68 + nt * 16 + l15] = acc[mt][nt][r];
        __syncthreads();

        // pack rows -> h1b bf16 (each thread: one half-row of 32 floats -> 4 uint4)
        int rr = t >> 1, hh = t & 1;
        int grow = row0 + rr;
        if (grow < N) {
            const float* sp = rows + rr * 68 + hh * 32;
            unsigned int u[16];
#pragma unroll
            for (int j = 0; j < 16; j++) u[j] = pack2(sp[2 * j], sp[2 * j + 1]);
            uint4* dp = (uint4*)(H1b + (size_t)grow * 32 + hh * 16);
            uint4 p0 = { u[0], u[1], u[2], u[3] };
            uint4 p1 = { u[4], u[5], u[6], u[7] };
            uint4 p2 = { u[8], u[9], u[10], u[11] };
            uint4 p3 = { u[12], u[13], u[14], u[15] };
            dp[0] = p0; dp[1] = p1; dp[2] = p2; dp[3] = p3;
        }
    }
}

// ---------------- csr: CSR build + degree-sort perm + sentinel pad + src-half order ----------------
// Each node's segment = [low-src run | high-src run | sentinel pads], 8-aligned.
// Edges staged in LDS (pre-filled with sentinel N) and flushed as 256 coalesced uint4 stores.

__global__ __launch_bounds__(TPB) void k_csr(
        const int* __restrict__ bcnt, const int* __restrict__ tmp,
        int* __restrict__ rowptr, unsigned short* __restrict__ rowlen,
        float* __restrict__ dinv, unsigned short* __restrict__ edges,
        unsigned short* __restrict__ perm, unsigned int* __restrict__ h1b,
        unsigned int* __restrict__ g2b, int N, int NHALF) {
    __shared__ int hist2[2 * BNODES];    // (node, half) counts
    __shared__ int cur2[2 * BNODES];     // dual write cursors
    __shared__ int lenl[BNODES];
    __shared__ int sh[BNODES];
    __shared__ unsigned short el[CAP];   // 4 KB staged edges
    int b = blockIdx.x;
    int t = threadIdx.x;
    int node0 = b << BSHIFT;
    int nn = N - node0; if (nn > BNODES) nn = BNODES;
    int cnt = bcnt[b]; if (cnt > CAP) cnt = CAP;
    const int tb = b * CAP;

    if (b == 0) {                              // zero the sentinel rows (row N)
        uint4 z = {0u, 0u, 0u, 0u};
        if (t < 8)  ((uint4*)(h1b + (size_t)N * 32))[t] = z;       // 128 B
        if (t >= 8 && t < 12) ((uint4*)(g2b + (size_t)N * 16))[t - 8] = z;  // 64 B
        if (t == 12) dinv[N] = 0.0f;
    }

    int v[8];                                  // stage bucket once: 256 thr x 8 = 2048 = CAP
#pragma unroll
    for (int i = 0; i < 8; i++) {
        int idx = t + i * TPB;
        v[i] = (idx < cnt) ? tmp[tb + idx] : -1;   // entries are >= 0 by construction
    }
    if (t < 2 * BNODES) hist2[t] = 0;
    {   // pre-fill staged edges with sentinel N (covers pad slots + unused tail)
        unsigned int sent2 = ((unsigned)N << 16) | (unsigned)N;
        unsigned int* el32 = (unsigned int*)el;
#pragma unroll
        for (int i = 0; i < CAP / 2 / TPB; i++) el32[t + i * TPB] = sent2;
    }
    __syncthreads();
#pragma unroll
    for (int i = 0; i < 8; i++)
        if (v[i] >= 0)
            atomicAdd(&hist2[((v[i] >> 16) << 1) + ((v[i] & 0xffff) >= NHALF)], 1);
    __syncthreads();
    if (t < BNODES) {
        int ll = hist2[2 * t], lh = hist2[2 * t + 1];
        lenl[t] = ll;
        sh[t] = (ll + lh + 7) & ~7;            // padded length (8-aligned segs)
    }
    __syncthreads();
    for (int o = 1; o < BNODES; o <<= 1) {     // inclusive scan of padded lengths
        int x = (t >= o && t < BNODES) ? sh[t - o] : 0;
        __syncthreads();
        if (t < BNODES) sh[t] += x;
        __syncthreads();
    }
    if (t < BNODES) {
        int len = hist2[2 * t] + hist2[2 * t + 1];
        int excl = sh[t] - ((len + 7) & ~7);   // multiple of 8
        cur2[2 * t] = excl;                    // low-src cursor
        cur2[2 * t + 1] = excl + lenl[t];      // high-src cursor
        float dv = rsqrtf((float)(len + 1));   // self-loop -> deg>=1
        if (t < nn) {
            dinv[node0 + t] = dv;
            rowptr[node0 + t] = tb + excl;
            rowlen[node0 + t] = (unsigned short)len;
            // degree-sorted rank within bucket (unique via index tie-break)
            int rank = 0;
            for (int j = 0; j < nn; j++) {
                int lj = hist2[2 * j] + hist2[2 * j + 1];
                rank += (lj < len) || (lj == len && j < t);
            }
            perm[node0 + rank] = (unsigned short)(node0 + t);
        }
    }
    __syncthreads();
#pragma unroll
    for (int i = 0; i < 8; i++) {              // scatter into LDS (low run, then high run)
        if (v[i] >= 0) {
            int node = v[i] >> 16;
            int half = (v[i] & 0xffff) >= NHALF;
            int pos = atomicAdd(&cur2[2 * node + half], 1);
            if (pos < CAP)                     // overflow guard (never hit)
                el[pos] = (unsigned short)(v[i] & 0xffff);
        }
    }
    __syncthreads();
    // coalesced flush: 2048 ushorts = 256 uint4 (tb is 4KB-aligned)
    ((uint4*)(edges + tb))[t] = ((const uint4*)el)[t];
}

// ---------------- gg: layer-1 aggregate + relu + GEMM2 -> g2 (bf16); 64 nodes/block ----------------

__global__ __launch_bounds__(TPBG) void k_gg(
        const int* __restrict__ rowptr, const unsigned short* __restrict__ rowlen,
        const unsigned short* __restrict__ edges,
        const unsigned int* __restrict__ h1b,
        const float* __restrict__ dinv, const float* __restrict__ b1,
        const float* __restrict__ W2, const unsigned short* __restrict__ perm,
        unsigned int* __restrict__ g2b, int N) {
    __shared__ float W2s[64 * 32];    // 8 KB
    __shared__ float rows[64 * 68];   // 17408 B
    __shared__ float dl[64];
    __shared__ int nst[64];
    __shared__ int nlen[64];
    __shared__ unsigned short pml[64];
    int t = threadIdx.x;
    int pos0 = blockIdx.x * 64;
    int nn = N - pos0; if (nn > 64) nn = 64;
    if (nn <= 0) return;

    {
        const float4* W4 = (const float4*)W2;
        ((float4*)W2s)[t] = W4[t];    // 512 x 16B = 2048 floats exact
    }
    if (t < nn) {
        int nd = perm[pos0 + t];
        pml[t] = (unsigned short)nd;
        dl[t] = dinv[nd];
        nst[t] = rowptr[nd];
        nlen[t] = rowlen[nd];
    }
    __syncthreads();

    const uint4* G4 = (const uint4*)h1b;   // 8 uint4 per 64-col row
    int nl = t >> 3;                        // 0..63
    int lane = t & 7;
    if (nl < nn) {
        float acc[8], f[8];
        float w0 = dl[nl];
        uint4 sv = G4[(size_t)pml[nl] * 8 + lane];
        dec8(sv, f);
#pragma unroll
        for (int k = 0; k < 8; k++) acc[k] = w0 * f[k];     // self term
        int base = nst[nl];
        int pd = (nlen[nl] + 7) & ~7;                       // padded length: full batches only
        for (int j = 0; j < pd; j += 8) {
            uint4 ev = *(const uint4*)(edges + base + j);    // 8 edge indices (pads -> N)
            int s[8];
            s[0] = ev.x & 0xffff; s[1] = ev.x >> 16;
            s[2] = ev.y & 0xffff; s[3] = ev.y >> 16;
            s[4] = ev.z & 0xffff; s[5] = ev.z >> 16;
            s[6] = ev.w & 0xffff; s[7] = ev.w >> 16;
            uint4 r[8]; float dv[8];
#pragma unroll
            for (int u = 0; u < 8; u++) {
                r[u] = G4[(size_t)s[u] * 8 + lane];
                dv[u] = dinv[s[u]];                          // dinv[N]=0 -> pad adds 0
            }
#pragma unroll
            for (int u = 0; u < 8; u++) {
                dec8(r[u], f);
#pragma unroll
                for (int k = 0; k < 8; k++) acc[k] = fmaf(dv[u], f[k], acc[k]);
            }
        }
        const float4* bb4 = (const float4*)(b1 + lane * 8);
        float4 ba = bb4[0], bc = bb4[1];
        float* rr = rows + nl * 68 + lane * 8;
        rr[0] = fmaxf(fmaf(acc[0], w0, ba.x), 0.0f);
        rr[1] = fmaxf(fmaf(acc[1], w0, ba.y), 0.0f);
        rr[2] = fmaxf(fmaf(acc[2], w0, ba.z), 0.0f);
        rr[3] = fmaxf(fmaf(acc[3], w0, ba.w), 0.0f);
        rr[4] = fmaxf(fmaf(acc[4], w0, bc.x), 0.0f);
        rr[5] = fmaxf(fmaf(acc[5], w0, bc.y), 0.0f);
        rr[6] = fmaxf(fmaf(acc[6], w0, bc.z), 0.0f);
        rr[7] = fmaxf(fmaf(acc[7], w0, bc.w), 0.0f);
    }
    __syncthreads();

    // gemm2: position n=t>>3 (0..63), cols 4c..4c+3 (c=t&7); writes g2[perm[n]] (bf16)
    int n = t >> 3;
    int c = t & 7;
    if (n < nn) {
        const float* row = rows + n * 68;
        float a0 = 0.0f, a1 = 0.0f, a2 = 0.0f, a3 = 0.0f;
#pragma unroll 8
        for (int k = 0; k < 64; k++) {
            float rv = row[k];
            const float* w = W2s + k * 32 + 4 * c;
            a0 = fmaf(rv, w[0], a0); a1 = fmaf(rv, w[1], a1);
            a2 = fmaf(rv, w[2], a2); a3 = fmaf(rv, w[3], a3);
        }
        float dv = dl[n];
        uint2 p = { pack2(a0 * dv, a1 * dv), pack2(a2 * dv, a3 * dv) };
        ((uint2*)g2b)[(size_t)pml[n] * 8 + c] = p;  // 32-col row = 8 uint2
    }
}

// ---------------- g32: layer-2 aggregate -> out (fp32); 64 nodes/block ----------------

__global__ __launch_bounds__(TPBG) void k_g32(
        const int* __restrict__ rowptr, const unsigned short* __restrict__ rowlen,
        const unsigned short* __restrict__ edges,
        const unsigned int* __restrict__ g2b,
        const float* __restrict__ dinv, const float* __restrict__ b2,
        const unsigned short* __restrict__ perm, float* __restrict__ out, int N) {
    __shared__ float dl[64];
    __shared__ int nst[64];
    __shared__ int nlen[64];
    __shared__ unsigned short pml[64];
    int t = threadIdx.x;
    int pos0 = blockIdx.x * 64;
    int nn = N - pos0; if (nn > 64) nn = 64;
    if (nn <= 0) return;
    if (t < nn) {
        int nd = perm[pos0 + t];
        pml[t] = (unsigned short)nd;
        dl[t] = dinv[nd];
        nst[t] = rowptr[nd];
        nlen[t] = rowlen[nd];
    }
    __syncthreads();

    int nl = t >> 3;                       // 0..63
    int lane = t & 7;
    if (nl >= nn) return;

    const uint2* G2 = (const uint2*)g2b;   // 8 uint2 per 32-col row
    float acc[4], f[4];
    uint2 sv = G2[(size_t)pml[nl] * 8 + lane];
    dec4(sv, acc);
    int base = nst[nl];
    int pd = (nlen[nl] + 7) & ~7;          // padded length (multiple of 8)
    int j = 0;
    for (; j + 15 < pd; j += 16) {
        uint4 ea = *(const uint4*)(edges + base + j);
        uint4 eb = *(const uint4*)(edges + base + j + 8);
        int s[16];
        s[0]  = ea.x & 0xffff; s[1]  = ea.x >> 16; s[2]  = ea.y & 0xffff; s[3]  = ea.y >> 16;
        s[4]  = ea.z & 0xffff; s[5]  = ea.z >> 16; s[6]  = ea.w & 0xffff; s[7]  = ea.w >> 16;
        s[8]  = eb.x & 0xffff; s[9]  = eb.x >> 16; s[10] = eb.y & 0xffff; s[11] = eb.y >> 16;
        s[12] = eb.z & 0xffff; s[13] = eb.z >> 16; s[14] = eb.w & 0xffff; s[15] = eb.w >> 16;
        uint2 r[16];
#pragma unroll
        for (int u = 0; u < 16; u++) r[u] = G2[(size_t)s[u] * 8 + lane];
#pragma unroll
        for (int u = 0; u < 16; u++) {
            dec4(r[u], f);
            acc[0] += f[0]; acc[1] += f[1]; acc[2] += f[2]; acc[3] += f[3];
        }
    }
    if (j < pd) {                           // at most one remaining 8-batch (pads -> row N = 0)
        uint4 ea = *(const uint4*)(edges + base + j);
        int s[8];
        s[0] = ea.x & 0xffff; s[1] = ea.x >> 16; s[2] = ea.y & 0xffff; s[3] = ea.y >> 16;
        s[4] = ea.z & 0xffff; s[5] = ea.z >> 16; s[6] = ea.w & 0xffff; s[7] = ea.w >> 16;
        uint2 r[8];
#pragma unroll
        for (int u = 0; u < 8; u++) r[u] = G2[(size_t)s[u] * 8 + lane];
#pragma unroll
        for (int u = 0; u < 8; u++) {
            dec4(r[u], f);
            acc[0] += f[0]; acc[1] += f[1]; acc[2] += f[2]; acc[3] += f[3];
        }
    }
    float w0 = dl[nl];
    const float4* bb4 = (const float4*)(b2 + lane * 4);
    float4 ba = bb4[0];
    float4 o0 = { fmaxf(fmaf(acc[0], w0, ba.x), 0.0f),
                  fmaxf(fmaf(acc[1], w0, ba.y), 0.0f),
                  fmaxf(fmaf(acc[2], w0, ba.z), 0.0f),
                  fmaxf(fmaf(acc[3], w0, ba.w), 0.0f) };
    *(float4*)(out + (size_t)pml[nl] * 32 + lane * 4) = o0;
}

static inline int cdiv(int a, int b) { return (a + b - 1) / b; }
static inline char* alignup(char* p) { return (char*)(((uintptr_t)p + 255) & ~(uintptr_t)255); }

extern "C" void kernel_launch(void* const* d_in, const int* in_sizes, int n_in,
                              void* d_out, int out_size, void* d_ws, size_t ws_size,
                              hipStream_t stream) {
    const float* x  = (const float*)d_in[0];
    const int*   ei = (const int*)d_in[1];
    const float* W1 = (const float*)d_in[2];
    const float* b1 = (const float*)d_in[3];
    const float* W2 = (const float*)d_in[4];
    const float* b2 = (const float*)d_in[5];
    float* out = (float*)d_out;

    int N = in_sizes[0] / 128;
    int E = in_sizes[1] / 2;
    const int* src = ei;
    const int* dst = ei + E;

    int NB = cdiv(N, BNODES);
    int NHALF = N / 2;

    char* p = (char*)d_ws;
    float* dinv  = (float*)p;            p = alignup(p + sizeof(float) * (N + 1));
    int* rowptr  = (int*)p;              p = alignup(p + sizeof(int) * N);
    unsigned short* rowlen = (unsigned short*)p;  p = alignup(p + sizeof(short) * N);
    unsigned short* perm = (unsigned short*)p;    p = alignup(p + sizeof(short) * N);
    int* bcnt    = (int*)p;              p = alignup(p + sizeof(int) * 1024);
    int* tmp     = (int*)p;              p = alignup(p + sizeof(int) * (size_t)NB * CAP);
    unsigned short* edges = (unsigned short*)p;   p = alignup(p + sizeof(short) * (size_t)NB * CAP);
    unsigned int* h1b = (unsigned int*)p; p = alignup(p + sizeof(short) * ((size_t)N + 1) * 64);
    unsigned int* g2b = (unsigned int*)p; p = alignup(p + sizeof(short) * ((size_t)N + 1) * 32);

    dim3 blk(TPB);
    int FB = cdiv(E, ACHUNK);        // 196 fill blocks
    int G1 = cdiv(N, GROWS);         // 391 gemm1 tiles (128 rows each)
    int fat = 1;                     // fill at bid%3==0, gemm else
    while ((fat + 2) / 3 < FB || fat - (fat + 2) / 3 < G1) fat++;

    hipMemsetAsync(bcnt, 0, sizeof(int) * 1024, stream);
    k_fat<<<fat, blk, 0, stream>>>(src, dst, E, bcnt, tmp, NB,
                                   x, W1, h1b, N, G1, FB);
    k_csr<<<NB, blk, 0, stream>>>(bcnt, tmp, rowptr, rowlen, dinv, edges, perm,
                                  h1b, g2b, N, NHALF);
    k_gg<<<cdiv(N, 64), dim3(TPBG), 0, stream>>>(rowptr, rowlen, edges, h1b,
                                                 dinv, b1, W2, perm, g2b, N);
    k_g32<<<cdiv(N, 64), dim3(TPBG), 0, stream>>>(rowptr, rowlen, edges, g2b,
                                                  dinv, b2, perm, out, N);
}

// Round 17
// 130.488 us; speedup vs baseline: 1.0277x; 1.0277x over previous
//
#include <hip/hip_runtime.h>

#define TPB 256
#define ACHUNK 4096        // edges per fill block (256 thr x 16, register-staged)
#define BSHIFT 6           // bucket = dst >> 6  (64 nodes/bucket)
#define BNODES 64
#define CAP 2048           // tmp capacity per bucket (mean 1024; padded CSR <= ~1.6K)
#define GROWS 128          // gemm1 tile rows
// gemm1 LDS: Xs bf16[128][136] = 34816 B, Wt bf16[64][136] = 17408 B
#define SMEMB 52224

typedef __attribute__((ext_vector_type(8))) short bf16x8;
typedef __attribute__((ext_vector_type(4))) float f32x4;

// ---- bf16 helpers (values finite; RNE encode) ----
__device__ __forceinline__ float blo(unsigned u) { return __uint_as_float(u << 16); }
__device__ __forceinline__ float bhi(unsigned u) { return __uint_as_float(u & 0xffff0000u); }
__device__ __forceinline__ unsigned pack2(float a, float b) {
    unsigned ua = __float_as_uint(a); ua += 0x7fffu + ((ua >> 16) & 1u);
    unsigned ub = __float_as_uint(b); ub += 0x7fffu + ((ub >> 16) & 1u);
    return (ua >> 16) | (ub & 0xffff0000u);
}
__device__ __forceinline__ void dec8(uint4 v, float* f) {
    f[0] = blo(v.x); f[1] = bhi(v.x); f[2] = blo(v.y); f[3] = bhi(v.y);
    f[4] = blo(v.z); f[5] = bhi(v.z); f[6] = blo(v.w); f[7] = bhi(v.w);
}
__device__ __forceinline__ void dec4(uint2 v, float* f) {
    f[0] = blo(v.x); f[1] = bhi(v.x); f[2] = blo(v.y); f[3] = bhi(v.y);
}

// ---------------- fat: fill (packed tmp, R1-verified) || GEMM1 via bf16 MFMA (R10) ----------------
// tmp[e] = (dst&63)<<16 | src   (src < 65536 since N=50000)
// h1b holds UNSCALED X@W1 rows bf16; dinv applied at gather time in k_gg.
// MFMA branch: 128x64 tile/block, 4 waves x (32 rows x 64 cols), K=128 in 4 steps of 32.
// C/D layout (HW-verified): col = lane&15, row = (lane>>4)*4 + reg.

__global__ __launch_bounds__(TPB) void k_fat(
        const int* __restrict__ src, const int* __restrict__ dst, int E,
        int* __restrict__ bcnt, int* __restrict__ tmp, int NB,
        const float* __restrict__ X, const float* __restrict__ W,
        unsigned int* __restrict__ H1b, int N, int G1, int FB) {
    __shared__ __align__(16) char smem[SMEMB];
    int bid = blockIdx.x;
    int t = threadIdx.x;

    if ((bid % 3) == 0) {
        int* lcnt = (int*)smem;
        int fidx = bid / 3;
        if (fidx >= FB) return;
        int c0 = fidx * ACHUNK;
        int s_[16], d_[16];
#pragma unroll
        for (int i = 0; i < 16; i++) {
            int e = c0 + i * TPB + t;
            if (e < E) { s_[i] = src[e]; d_[i] = dst[e]; }
            else d_[i] = -1;
        }
        for (int b = t; b < NB; b += TPB) lcnt[b] = 0;
        __syncthreads();
#pragma unroll
        for (int i = 0; i < 16; i++)
            if (d_[i] >= 0) atomicAdd(&lcnt[d_[i] >> BSHIFT], 1);
        __syncthreads();
        for (int b = t; b < NB; b += TPB) {
            int c = lcnt[b];
            lcnt[b] = c ? (b * CAP + atomicAdd(&bcnt[b], c)) : 0;
        }
        __syncthreads();
#pragma unroll
        for (int i = 0; i < 16; i++) {
            if (d_[i] >= 0) {
                int bkt = d_[i] >> BSHIFT;
                int pos = atomicAdd(&lcnt[bkt], 1);
                if (pos < (bkt + 1) * CAP) {   // overflow guard (never hit)
                    tmp[pos] = ((d_[i] & (BNODES - 1)) << 16) | s_[i];
                }
            }
        }
    } else {
        int gb = bid - bid / 3 - 1;
        if (gb >= G1) return;
        int row0 = gb * GROWS;

        unsigned int* XsU32 = (unsigned int*)smem;             // [128][68] uints
        unsigned int* WtU32 = (unsigned int*)(smem + 34816);   // [64][68] uints
        const unsigned short* XsU = (const unsigned short*)smem;
        const unsigned short* WtU = (const unsigned short*)(smem + 34816);

        // stage X tile -> bf16 (row-major, padded stride 136 bf16)
        const float4* X4 = (const float4*)X;
#pragma unroll
        for (int i = 0; i < 16; i++) {
            int q = t + i * 256;          // 0..4095
            int r = q >> 5, c4 = q & 31;
            int gr = row0 + r; if (gr >= N) gr = N - 1;
            float4 v = X4[(size_t)gr * 32 + c4];
            unsigned int* dptr = XsU32 + r * 68 + c4 * 2;
            dptr[0] = pack2(v.x, v.y);
            dptr[1] = pack2(v.z, v.w);
        }
        // stage W1 TRANSPOSED -> bf16: Wt[col][k] (pairs along k)
#pragma unroll
        for (int i = 0; i < 16; i++) {
            int q = t + i * 256;          // 0..4095
            int col = q & 63, kp = q >> 6; // kp 0..63
            float w0 = W[(size_t)(2 * kp) * 64 + col];
            float w1 = W[(size_t)(2 * kp + 1) * 64 + col];
            WtU32[col * 68 + kp] = pack2(w0, w1);
        }
        __syncthreads();

        int lane = t & 63;
        int wv = t >> 6;                  // 4 waves: rows [wv*32, wv*32+32)
        int l15 = lane & 15;
        int lg = lane >> 4;
        f32x4 zero = {0.0f, 0.0f, 0.0f, 0.0f};
        f32x4 acc[2][4];
#pragma unroll
        for (int mt = 0; mt < 2; mt++)
#pragma unroll
            for (int nt = 0; nt < 4; nt++) acc[mt][nt] = zero;

#pragma unroll
        for (int kk = 0; kk < 4; kk++) {
            int ko = kk * 32 + lg * 8;    // bf16 index within row, 16B-aligned
            bf16x8 a0 = *reinterpret_cast<const bf16x8*>(XsU + (wv * 32 + l15) * 136 + ko);
            bf16x8 a1 = *reinterpret_cast<const bf16x8*>(XsU + (wv * 32 + 16 + l15) * 136 + ko);
            bf16x8 b[4];
#pragma unroll
            for (int nt = 0; nt < 4; nt++)
                b[nt] = *reinterpret_cast<const bf16x8*>(WtU + (nt * 16 + l15) * 136 + ko);
#pragma unroll
            for (int nt = 0; nt < 4; nt++) {
                acc[0][nt] = __builtin_amdgcn_mfma_f32_16x16x32_bf16(a0, b[nt], acc[0][nt], 0, 0, 0);
                acc[1][nt] = __builtin_amdgcn_mfma_f32_16x16x32_bf16(a1, b[nt], acc[1][nt], 0, 0, 0);
            }
        }
        __syncthreads();                   // done reading Xs; reuse as fp32 rows[128][68]

        float* rows = (float*)smem;
#pragma unroll
        for (int mt = 0; mt < 2; mt++)
#pragma unroll
            for (int nt = 0; nt < 4; nt++)
#pragma unroll
                for (int r = 0; r < 4; r++)
                    rows[(wv * 32 + mt * 16 + lg * 4 + r) * 68 + nt * 16 + l15] = acc[mt][nt][r];
        __syncthreads();

        // pack rows -> h1b bf16 (each thread: one half-row of 32 floats -> 4 uint4)
        int rr = t >> 1, hh = t & 1;
        int grow = row0 + rr;
        if (grow < N) {
            const float* sp = rows + rr * 68 + hh * 32;
            unsigned int u[16];
#pragma unroll
            for (int j = 0; j < 16; j++) u[j] = pack2(sp[2 * j], sp[2 * j + 1]);
            uint4* dp = (uint4*)(H1b + (size_t)grow * 32 + hh * 16);
            uint4 p0 = { u[0], u[1], u[2], u[3] };
            uint4 p1 = { u[4], u[5], u[6], u[7] };
            uint4 p2 = { u[8], u[9], u[10], u[11] };
            uint4 p3 = { u[12], u[13], u[14], u[15] };
            dp[0] = p0; dp[1] = p1; dp[2] = p2; dp[3] = p3;
        }
    }
}

// ---------------- csr: CSR build + degree-sort perm + sentinel pad + src-half order ----------------
// Each node's segment = [low-src run | high-src run | sentinel pads], 8-aligned.
// Edges staged in LDS (pre-filled with sentinel N) and flushed as 256 coalesced uint4 stores.

__global__ __launch_bounds__(TPB) void k_csr(
        const int* __restrict__ bcnt, const int* __restrict__ tmp,
        int* __restrict__ rowptr, unsigned short* __restrict__ rowlen,
        float* __restrict__ dinv, unsigned short* __restrict__ edges,
        unsigned short* __restrict__ perm, unsigned int* __restrict__ h1b,
        unsigned int* __restrict__ g2b, int N, int NHALF) {
    __shared__ int hist2[2 * BNODES];    // (node, half) counts
    __shared__ int cur2[2 * BNODES];     // dual write cursors
    __shared__ int lenl[BNODES];
    __shared__ int sh[BNODES];
    __shared__ unsigned short el[CAP];   // 4 KB staged edges
    int b = blockIdx.x;
    int t = threadIdx.x;
    int node0 = b << BSHIFT;
    int nn = N - node0; if (nn > BNODES) nn = BNODES;
    int cnt = bcnt[b]; if (cnt > CAP) cnt = CAP;
    const int tb = b * CAP;

    if (b == 0) {                              // zero the sentinel rows (row N)
        uint4 z = {0u, 0u, 0u, 0u};
        if (t < 8)  ((uint4*)(h1b + (size_t)N * 32))[t] = z;       // 128 B
        if (t >= 8 && t < 12) ((uint4*)(g2b + (size_t)N * 16))[t - 8] = z;  // 64 B
        if (t == 12) dinv[N] = 0.0f;
    }

    int v[8];                                  // stage bucket once: 256 thr x 8 = 2048 = CAP
#pragma unroll
    for (int i = 0; i < 8; i++) {
        int idx = t + i * TPB;
        v[i] = (idx < cnt) ? tmp[tb + idx] : -1;   // entries are >= 0 by construction
    }
    if (t < 2 * BNODES) hist2[t] = 0;
    {   // pre-fill staged edges with sentinel N (covers pad slots + unused tail)
        unsigned int sent2 = ((unsigned)N << 16) | (unsigned)N;
        unsigned int* el32 = (unsigned int*)el;
#pragma unroll
        for (int i = 0; i < CAP / 2 / TPB; i++) el32[t + i * TPB] = sent2;
    }
    __syncthreads();
#pragma unroll
    for (int i = 0; i < 8; i++)
        if (v[i] >= 0)
            atomicAdd(&hist2[((v[i] >> 16) << 1) + ((v[i] & 0xffff) >= NHALF)], 1);
    __syncthreads();
    if (t < BNODES) {
        int ll = hist2[2 * t], lh = hist2[2 * t + 1];
        lenl[t] = ll;
        sh[t] = (ll + lh + 7) & ~7;            // padded length (8-aligned segs)
    }
    __syncthreads();
    for (int o = 1; o < BNODES; o <<= 1) {     // inclusive scan of padded lengths
        int x = (t >= o && t < BNODES) ? sh[t - o] : 0;
        __syncthreads();
        if (t < BNODES) sh[t] += x;
        __syncthreads();
    }
    if (t < BNODES) {
        int len = hist2[2 * t] + hist2[2 * t + 1];
        int excl = sh[t] - ((len + 7) & ~7);   // multiple of 8
        cur2[2 * t] = excl;                    // low-src cursor
        cur2[2 * t + 1] = excl + lenl[t];      // high-src cursor
        float dv = rsqrtf((float)(len + 1));   // self-loop -> deg>=1
        if (t < nn) {
            dinv[node0 + t] = dv;
            rowptr[node0 + t] = tb + excl;
            rowlen[node0 + t] = (unsigned short)len;
            // degree-sorted rank within bucket (unique via index tie-break)
            int rank = 0;
            for (int j = 0; j < nn; j++) {
                int lj = hist2[2 * j] + hist2[2 * j + 1];
                rank += (lj < len) || (lj == len && j < t);
            }
            perm[node0 + rank] = (unsigned short)(node0 + t);
        }
    }
    __syncthreads();
#pragma unroll
    for (int i = 0; i < 8; i++) {              // scatter into LDS (low run, then high run)
        if (v[i] >= 0) {
            int node = v[i] >> 16;
            int half = (v[i] & 0xffff) >= NHALF;
            int pos = atomicAdd(&cur2[2 * node + half], 1);
            if (pos < CAP)                     // overflow guard (never hit)
                el[pos] = (unsigned short)(v[i] & 0xffff);
        }
    }
    __syncthreads();
    // coalesced flush: 2048 ushorts = 256 uint4 (tb is 4KB-aligned)
    ((uint4*)(edges + tb))[t] = ((const uint4*)el)[t];
}

// ---------------- gg: layer-1 aggregate + relu + GEMM2 -> g2 (bf16); full batches only ----------------

__global__ __launch_bounds__(TPB) void k_gg(
        const int* __restrict__ rowptr, const unsigned short* __restrict__ rowlen,
        const unsigned short* __restrict__ edges,
        const unsigned int* __restrict__ h1b,
        const float* __restrict__ dinv, const float* __restrict__ b1,
        const float* __restrict__ W2, const unsigned short* __restrict__ perm,
        unsigned int* __restrict__ g2b, int N) {
    __shared__ float W2s[64 * 32];   // 8 KB
    __shared__ float rows[32 * 68];  // 8.5 KB
    __shared__ float dl[32];
    __shared__ int nst[32];
    __shared__ int nlen[32];
    __shared__ unsigned short pml[32];
    int t = threadIdx.x;
    int pos0 = blockIdx.x * 32;
    int nn = N - pos0; if (nn > 32) nn = 32;
    if (nn <= 0) return;

    {
        const float4* W4 = (const float4*)W2;
        float4* Wd = (float4*)W2s;
        Wd[t] = W4[t]; Wd[t + 256] = W4[t + 256];
    }
    if (t < nn) {
        int nd = perm[pos0 + t];
        pml[t] = (unsigned short)nd;
        dl[t] = dinv[nd];
        nst[t] = rowptr[nd];
        nlen[t] = rowlen[nd];
    }
    __syncthreads();

    const uint4* G4 = (const uint4*)h1b;   // 8 uint4 per 64-col row
    int nl = t >> 3;
    int lane = t & 7;
    if (nl < nn) {
        float acc[8], f[8];
        float w0 = dl[nl];
        uint4 sv = G4[(size_t)pml[nl] * 8 + lane];
        dec8(sv, f);
#pragma unroll
        for (int k = 0; k < 8; k++) acc[k] = w0 * f[k];     // self term
        int base = nst[nl];
        int pd = (nlen[nl] + 7) & ~7;                       // padded length: full batches only
        for (int j = 0; j < pd; j += 8) {
            uint4 ev = *(const uint4*)(edges + base + j);    // 8 edge indices (pads -> N)
            int s[8];
            s[0] = ev.x & 0xffff; s[1] = ev.x >> 16;
            s[2] = ev.y & 0xffff; s[3] = ev.y >> 16;
            s[4] = ev.z & 0xffff; s[5] = ev.z >> 16;
            s[6] = ev.w & 0xffff; s[7] = ev.w >> 16;
            uint4 r[8]; float dv[8];
#pragma unroll
            for (int u = 0; u < 8; u++) {
                r[u] = G4[(size_t)s[u] * 8 + lane];
                dv[u] = dinv[s[u]];                          // dinv[N]=0 -> pad adds 0
            }
#pragma unroll
            for (int u = 0; u < 8; u++) {
                dec8(r[u], f);
#pragma unroll
                for (int k = 0; k < 8; k++) acc[k] = fmaf(dv[u], f[k], acc[k]);
            }
        }
        const float4* bb4 = (const float4*)(b1 + lane * 8);
        float4 ba = bb4[0], bc = bb4[1];
        float* rr = rows + nl * 68 + lane * 8;
        rr[0] = fmaxf(fmaf(acc[0], w0, ba.x), 0.0f);
        rr[1] = fmaxf(fmaf(acc[1], w0, ba.y), 0.0f);
        rr[2] = fmaxf(fmaf(acc[2], w0, ba.z), 0.0f);
        rr[3] = fmaxf(fmaf(acc[3], w0, ba.w), 0.0f);
        rr[4] = fmaxf(fmaf(acc[4], w0, bc.x), 0.0f);
        rr[5] = fmaxf(fmaf(acc[5], w0, bc.y), 0.0f);
        rr[6] = fmaxf(fmaf(acc[6], w0, bc.z), 0.0f);
        rr[7] = fmaxf(fmaf(acc[7], w0, bc.w), 0.0f);
    }
    __syncthreads();

    // gemm2: position n=t>>3, cols 4c..4c+3 (c=t&7); writes g2[perm[n]] = dinv*h2 (bf16)
    int n = t >> 3;
    int c = t & 7;
    if (n < nn) {
        const float* row = rows + n * 68;
        float a0 = 0.0f, a1 = 0.0f, a2 = 0.0f, a3 = 0.0f;
#pragma unroll 8
        for (int k = 0; k < 64; k++) {
            float rv = row[k];
            const float* w = W2s + k * 32 + 4 * c;
            a0 = fmaf(rv, w[0], a0); a1 = fmaf(rv, w[1], a1);
            a2 = fmaf(rv, w[2], a2); a3 = fmaf(rv, w[3], a3);
        }
        float dv = dl[n];
        uint2 p = { pack2(a0 * dv, a1 * dv), pack2(a2 * dv, a3 * dv) };
        ((uint2*)g2b)[(size_t)pml[n] * 8 + c] = p;  // 32-col row = 8 uint2
    }
}

// ---------------- g32: layer-2 aggregate -> out (fp32); full batches only ----------------

__global__ __launch_bounds__(TPB) void k_g32(
        const int* __restrict__ rowptr, const unsigned short* __restrict__ rowlen,
        const unsigned short* __restrict__ edges,
        const unsigned int* __restrict__ g2b,
        const float* __restrict__ dinv, const float* __restrict__ b2,
        const unsigned short* __restrict__ perm, float* __restrict__ out, int N) {
    __shared__ float dl[32];
    __shared__ int nst[32];
    __shared__ int nlen[32];
    __shared__ unsigned short pml[32];
    int t = threadIdx.x;
    int pos0 = blockIdx.x * 32;
    int nn = N - pos0; if (nn > 32) nn = 32;
    if (nn <= 0) return;
    if (t < nn) {
        int nd = perm[pos0 + t];
        pml[t] = (unsigned short)nd;
        dl[t] = dinv[nd];
        nst[t] = rowptr[nd];
        nlen[t] = rowlen[nd];
    }
    __syncthreads();

    int nl = t >> 3;
    int lane = t & 7;
    if (nl >= nn) return;

    const uint2* G2 = (const uint2*)g2b;   // 8 uint2 per 32-col row
    float acc[4], f[4];
    uint2 sv = G2[(size_t)pml[nl] * 8 + lane];
    dec4(sv, acc);
    int base = nst[nl];
    int pd = (nlen[nl] + 7) & ~7;          // padded length (multiple of 8)
    int j = 0;
    for (; j + 15 < pd; j += 16) {
        uint4 ea = *(const uint4*)(edges + base + j);
        uint4 eb = *(const uint4*)(edges + base + j + 8);
        int s[16];
        s[0]  = ea.x & 0xffff; s[1]  = ea.x >> 16; s[2]  = ea.y & 0xffff; s[3]  = ea.y >> 16;
        s[4]  = ea.z & 0xffff; s[5]  = ea.z >> 16; s[6]  = ea.w & 0xffff; s[7]  = ea.w >> 16;
        s[8]  = eb.x & 0xffff; s[9]  = eb.x >> 16; s[10] = eb.y & 0xffff; s[11] = eb.y >> 16;
        s[12] = eb.z & 0xffff; s[13] = eb.z >> 16; s[14] = eb.w & 0xffff; s[15] = eb.w >> 16;
        uint2 r[16];
#pragma unroll
        for (int u = 0; u < 16; u++) r[u] = G2[(size_t)s[u] * 8 + lane];
#pragma unroll
        for (int u = 0; u < 16; u++) {
            dec4(r[u], f);
            acc[0] += f[0]; acc[1] += f[1]; acc[2] += f[2]; acc[3] += f[3];
        }
    }
    if (j < pd) {                           // at most one remaining 8-batch (pads -> row N = 0)
        uint4 ea = *(const uint4*)(edges + base + j);
        int s[8];
        s[0] = ea.x & 0xffff; s[1] = ea.x >> 16; s[2] = ea.y & 0xffff; s[3] = ea.y >> 16;
        s[4] = ea.z & 0xffff; s[5] = ea.z >> 16; s[6] = ea.w & 0xffff; s[7] = ea.w >> 16;
        uint2 r[8];
#pragma unroll
        for (int u = 0; u < 8; u++) r[u] = G2[(size_t)s[u] * 8 + lane];
#pragma unroll
        for (int u = 0; u < 8; u++) {
            dec4(r[u], f);
            acc[0] += f[0]; acc[1] += f[1]; acc[2] += f[2]; acc[3] += f[3];
        }
    }
    float w0 = dl[nl];
    const float4* bb4 = (const float4*)(b2 + lane * 4);
    float4 ba = bb4[0];
    float4 o0 = { fmaxf(fmaf(acc[0], w0, ba.x), 0.0f),
                  fmaxf(fmaf(acc[1], w0, ba.y), 0.0f),
                  fmaxf(fmaf(acc[2], w0, ba.z), 0.0f),
                  fmaxf(fmaf(acc[3], w0, ba.w), 0.0f) };
    *(float4*)(out + (size_t)pml[nl] * 32 + lane * 4) = o0;
}

static inline int cdiv(int a, int b) { return (a + b - 1) / b; }
static inline char* alignup(char* p) { return (char*)(((uintptr_t)p + 255) & ~(uintptr_t)255); }

extern "C" void kernel_launch(void* const* d_in, const int* in_sizes, int n_in,
                              void* d_out, int out_size, void* d_ws, size_t ws_size,
                              hipStream_t stream) {
    const float* x  = (const float*)d_in[0];
    const int*   ei = (const int*)d_in[1];
    const float* W1 = (const float*)d_in[2];
    const float* b1 = (const float*)d_in[3];
    const float* W2 = (const float*)d_in[4];
    const float* b2 = (const float*)d_in[5];
    float* out = (float*)d_out;

    int N = in_sizes[0] / 128;
    int E = in_sizes[1] / 2;
    const int* src = ei;
    const int* dst = ei + E;

    int NB = cdiv(N, BNODES);
    int NHALF = N / 2;

    char* p = (char*)d_ws;
    float* dinv  = (float*)p;            p = alignup(p + sizeof(float) * (N + 1));
    int* rowptr  = (int*)p;              p = alignup(p + sizeof(int) * N);
    unsigned short* rowlen = (unsigned short*)p;  p = alignup(p + sizeof(short) * N);
    unsigned short* perm = (unsigned short*)p;    p = alignup(p + sizeof(short) * N);
    int* bcnt    = (int*)p;              p = alignup(p + sizeof(int) * 1024);
    int* tmp     = (int*)p;              p = alignup(p + sizeof(int) * (size_t)NB * CAP);
    unsigned short* edges = (unsigned short*)p;   p = alignup(p + sizeof(short) * (size_t)NB * CAP);
    unsigned int* h1b = (unsigned int*)p; p = alignup(p + sizeof(short) * ((size_t)N + 1) * 64);
    unsigned int* g2b = (unsigned int*)p; p = alignup(p + sizeof(short) * ((size_t)N + 1) * 32);

    dim3 blk(TPB);
    int FB = cdiv(E, ACHUNK);        // 196 fill blocks
    int G1 = cdiv(N, GROWS);         // 391 gemm1 tiles (128 rows each)
    int fat = 1;                     // fill at bid%3==0, gemm else
    while ((fat + 2) / 3 < FB || fat - (fat + 2) / 3 < G1) fat++;

    hipMemsetAsync(bcnt, 0, sizeof(int) * 1024, stream);
    k_fat<<<fat, blk, 0, stream>>>(src, dst, E, bcnt, tmp, NB,
                                   x, W1, h1b, N, G1, FB);
    k_csr<<<NB, blk, 0, stream>>>(bcnt, tmp, rowptr, rowlen, dinv, edges, perm,
                                  h1b, g2b, N, NHALF);
    k_gg<<<cdiv(N, 32), blk, 0, stream>>>(rowptr, rowlen, edges, h1b,
                                          dinv, b1, W2, perm, g2b, N);
    k_g32<<<cdiv(N, 32), blk, 0, stream>>>(rowptr, rowlen, edges, g2b,
                                           dinv, b2, perm, out, N);
}